// Round 6
// baseline (908.481 us; speedup 1.0000x reference)
//
#include <hip/hip_runtime.h>
#include <math.h>

#define BB 256
#define TT 1024
#define KK 128
#define NB 16                 // batches per forward block (MFMA M/N dim)
#define NBLK (BB / NB)        // 16 forward blocks
#define NTHR 256              // 4 waves; each wave owns j-tiles w and w+4
#define CHUNK 4
#define NCHUNK (TT / CHUNK)   // 256
#define PSTR 136              // ushorts per P row (272 B)

typedef __attribute__((ext_vector_type(8))) short bf16x8;
typedef __attribute__((ext_vector_type(4))) float f32x4;

__global__ void zero_out_kernel(float* out) { out[0] = 0.0f; }

// RNE float -> bf16 bits
__device__ __forceinline__ unsigned short f2bf(float x) {
    unsigned b = __float_as_uint(x);
    return (unsigned short)((b + 0x7FFFu + ((b >> 16) & 1u)) >> 16);
}

// LGKM-only barrier: LDS is the only cross-wave dependency in the hot loop;
// global prefetch loads stay in flight across step barriers (never drain vmcnt).
#define BARSYNC() { asm volatile("s_waitcnt lgkmcnt(0)" ::: "memory"); \
                    __builtin_amdgcn_s_barrier(); \
                    asm volatile("" ::: "memory"); }

// Build E fragment (hi/lo bf16 split of E = exp(trans)) for k = kbase..kbase+7, col jc.
__device__ __forceinline__ void ldb(const float* __restrict__ trans, int kbase, int jc,
                                    bf16x8& BH, bf16x8& BL) {
#pragma unroll
    for (int e = 0; e < 8; ++e) {
        float v = expf(trans[(size_t)(kbase + e) * KK + jc]);
        unsigned short hb = f2bf(v);
        float hv = __uint_as_float(((unsigned)hb) << 16);
        BH[e] = (short)hb;
        BL[e] = (short)f2bf(v - hv);
    }
}

// ---------------- forward (denominator) kernel: 16 blocks x 256 threads ----------------
// 4 waves; wave w computes j-tiles {w, w+4}. P (B operand) is read from LDS ONCE
// per wave per step and reused for both tiles -> P-read LDS traffic halves vs the
// 8-wave version (which was LDS-pipe-bound at 8x P redundancy). Each lane's C
// fragments hold 4 consecutive j of ONE batch r per tile. Renorm every 4th step.
__global__ __launch_bounds__(NTHR, 1) void crf_fwd(
    const float* __restrict__ inputs,
    const float* __restrict__ trans,
    const int* __restrict__ mask,
    float* __restrict__ out)
{
    __shared__ __align__(16) unsigned short pbuf[2][NB * PSTR];
    __shared__ __align__(16) float ebuf[2][CHUNK * NB * KK];
    __shared__ float mbuf[2][CHUNK * NB];

    const int tid = threadIdx.x;
    const int l   = tid & 63;
    const int w   = tid >> 6;            // wave id 0..3
    const int r   = l & 15;              // C column = batch row
    const int kg  = l >> 4;              // k-group 0..3
    const int jca = w * 16 + (l & 15);   // E column, tile a
    const int jcb = jca + 64;            // E column, tile b
    const int j0a = w * 16 + kg * 4;     // C rows (tile a): lane owns j0a..j0a+3 of batch r
    const int j0b = j0a + 64;            // C rows (tile b)
    const int b0  = blockIdx.x * NB;

    // staging: 256 threads x 8 float4 per chunk (4 steps x 16 rows x 32 granules)
    const int kq2 = tid & 31;            // granule 0..31
    const int bbA = tid >> 5;            // rows 0..7
    const int bbB = bbA + 8;             // rows 8..15
    const float* gA = inputs + (size_t)(b0 + bbA) * TT * KK + (size_t)kq2 * 4;
    const float* gB = inputs + (size_t)(b0 + bbB) * TT * KK + (size_t)kq2 * 4;
    const int xwA = ((kq2 ^ bbA) << 2);  // swizzled store offset (floats)
    const int xwB = ((kq2 ^ bbB) << 2);
    const int xga = (((w * 4 + kg) ^ r) << 2);   // swizzled load granule (tile a)
    // tile b granule = (w*4+kg+16)^r = (tile-a granule)+16 (r<16) -> +64 floats

    // ---- E fragments for both tiles: hi+lo bf16 ----
    bf16x8 Aha0, Aha1, Aha2, Aha3, Ala0, Ala1, Ala2, Ala3;
    bf16x8 Ahb0, Ahb1, Ahb2, Ahb3, Alb0, Alb1, Alb2, Alb3;
    ldb(trans,  0 + kg * 8, jca, Aha0, Ala0);
    ldb(trans, 32 + kg * 8, jca, Aha1, Ala1);
    ldb(trans, 64 + kg * 8, jca, Aha2, Ala2);
    ldb(trans, 96 + kg * 8, jca, Aha3, Ala3);
    ldb(trans,  0 + kg * 8, jcb, Ahb0, Alb0);
    ldb(trans, 32 + kg * 8, jcb, Ahb1, Alb1);
    ldb(trans, 64 + kg * 8, jcb, Ahb2, Alb2);
    ldb(trans, 96 + kg * 8, jcb, Ahb3, Alb3);

#define XSTORE(DST, PF, I) { \
    PF.x = __expf(PF.x); PF.y = __expf(PF.y); PF.z = __expf(PF.z); PF.w = __expf(PF.w); \
    *(float4*)&DST[((((I) >> 1) * NB) + (((I) & 1) ? bbB : bbA)) * KK + (((I) & 1) ? xwB : xwA)] = PF; }

    // ---- stage chunk 0 of X = exp(emissions), + mask ----
    {
        float4 p0 = *(const float4*)(gA + 0 * (size_t)KK);
        float4 p1 = *(const float4*)(gB + 0 * (size_t)KK);
        float4 p2 = *(const float4*)(gA + 1 * (size_t)KK);
        float4 p3 = *(const float4*)(gB + 1 * (size_t)KK);
        float4 p4 = *(const float4*)(gA + 2 * (size_t)KK);
        float4 p5 = *(const float4*)(gB + 2 * (size_t)KK);
        float4 p6 = *(const float4*)(gA + 3 * (size_t)KK);
        float4 p7 = *(const float4*)(gB + 3 * (size_t)KK);
        float* d0 = ebuf[0];
        XSTORE(d0, p0, 0) XSTORE(d0, p1, 1) XSTORE(d0, p2, 2) XSTORE(d0, p3, 3)
        XSTORE(d0, p4, 4) XSTORE(d0, p5, 5) XSTORE(d0, p6, 6) XSTORE(d0, p7, 7)
    }
    if (tid < CHUNK * NB) {
        int s = tid >> 4, bq = tid & 15;
        mbuf[0][s * NB + bq] = (float)mask[(size_t)(b0 + bq) * TT + s];
    }
    BARSYNC();

    // ---- t = 0: p = exp(alpha0) = X[0], m = 0 ----
    float pa0, pa1, pa2, pa3, pb0, pb1, pb2, pb3;
    int m_int = 0;
    {
        float4 pca = *(const float4*)&ebuf[0][(0 * NB + r) * KK + xga];
        float4 pcb = *(const float4*)&ebuf[0][(0 * NB + r) * KK + xga + 64];
        pa0 = pca.x; pa1 = pca.y; pa2 = pca.z; pa3 = pca.w;
        pb0 = pcb.x; pb1 = pcb.y; pb2 = pcb.z; pb3 = pcb.w;
        unsigned ql, qh;
        asm volatile("v_cvt_pk_bf16_f32 %0, %1, %2" : "=v"(ql) : "v"(pa0), "v"(pa1));
        asm volatile("v_cvt_pk_bf16_f32 %0, %1, %2" : "=v"(qh) : "v"(pa2), "v"(pa3));
        *(uint2*)&pbuf[0][r * PSTR + j0a] = make_uint2(ql, qh);
        asm volatile("v_cvt_pk_bf16_f32 %0, %1, %2" : "=v"(ql) : "v"(pb0), "v"(pb1));
        asm volatile("v_cvt_pk_bf16_f32 %0, %1, %2" : "=v"(qh) : "v"(pb2), "v"(pb3));
        *(uint2*)&pbuf[0][r * PSTR + j0b] = make_uint2(ql, qh);
    }
    BARSYNC();

// One recursion step. S = step-in-chunk (compile-time), RN = renorm this step.
// Pp parity = (S-1)&1 ; Pn parity = S&1 (CHUNK=4 even).
#define STEP(S, RN) { \
    const unsigned short* Pp = pbuf[((S) + 1) & 1]; \
    unsigned short* Pn = pbuf[(S) & 1]; \
    float4 xva = *(const float4*)&eb[((S) * NB + r) * KK + xga]; \
    float4 xvb = *(const float4*)&eb[((S) * NB + r) * KK + xga + 64]; \
    float mi = mb[(S) * NB + r]; \
    const unsigned short* pr = Pp + r * PSTR + kg * 8; \
    union { uint4 q; bf16x8 v; } a0, a1, a2, a3; \
    a0.q = *(const uint4*)(pr); \
    a1.q = *(const uint4*)(pr + 32); \
    a2.q = *(const uint4*)(pr + 64); \
    a3.q = *(const uint4*)(pr + 96); \
    f32x4 accha = {0.f, 0.f, 0.f, 0.f}; \
    f32x4 accla = {0.f, 0.f, 0.f, 0.f}; \
    f32x4 acchb = {0.f, 0.f, 0.f, 0.f}; \
    f32x4 acclb = {0.f, 0.f, 0.f, 0.f}; \
    accha = __builtin_amdgcn_mfma_f32_16x16x32_bf16(Aha0, a0.v, accha, 0, 0, 0); \
    acchb = __builtin_amdgcn_mfma_f32_16x16x32_bf16(Ahb0, a0.v, acchb, 0, 0, 0); \
    accla = __builtin_amdgcn_mfma_f32_16x16x32_bf16(Ala0, a0.v, accla, 0, 0, 0); \
    acclb = __builtin_amdgcn_mfma_f32_16x16x32_bf16(Alb0, a0.v, acclb, 0, 0, 0); \
    accha = __builtin_amdgcn_mfma_f32_16x16x32_bf16(Aha1, a1.v, accha, 0, 0, 0); \
    acchb = __builtin_amdgcn_mfma_f32_16x16x32_bf16(Ahb1, a1.v, acchb, 0, 0, 0); \
    accla = __builtin_amdgcn_mfma_f32_16x16x32_bf16(Ala1, a1.v, accla, 0, 0, 0); \
    acclb = __builtin_amdgcn_mfma_f32_16x16x32_bf16(Alb1, a1.v, acclb, 0, 0, 0); \
    accha = __builtin_amdgcn_mfma_f32_16x16x32_bf16(Aha2, a2.v, accha, 0, 0, 0); \
    acchb = __builtin_amdgcn_mfma_f32_16x16x32_bf16(Ahb2, a2.v, acchb, 0, 0, 0); \
    accla = __builtin_amdgcn_mfma_f32_16x16x32_bf16(Ala2, a2.v, accla, 0, 0, 0); \
    acclb = __builtin_amdgcn_mfma_f32_16x16x32_bf16(Alb2, a2.v, acclb, 0, 0, 0); \
    accha = __builtin_amdgcn_mfma_f32_16x16x32_bf16(Aha3, a3.v, accha, 0, 0, 0); \
    acchb = __builtin_amdgcn_mfma_f32_16x16x32_bf16(Ahb3, a3.v, acchb, 0, 0, 0); \
    accla = __builtin_amdgcn_mfma_f32_16x16x32_bf16(Ala3, a3.v, accla, 0, 0, 0); \
    acclb = __builtin_amdgcn_mfma_f32_16x16x32_bf16(Alb3, a3.v, acclb, 0, 0, 0); \
    float na0 = (mi != 0.0f) ? (accha[0] + accla[0]) * xva.x : pa0; \
    float na1 = (mi != 0.0f) ? (accha[1] + accla[1]) * xva.y : pa1; \
    float na2 = (mi != 0.0f) ? (accha[2] + accla[2]) * xva.z : pa2; \
    float na3 = (mi != 0.0f) ? (accha[3] + accla[3]) * xva.w : pa3; \
    float nb0 = (mi != 0.0f) ? (acchb[0] + acclb[0]) * xvb.x : pb0; \
    float nb1 = (mi != 0.0f) ? (acchb[1] + acclb[1]) * xvb.y : pb1; \
    float nb2 = (mi != 0.0f) ? (acchb[2] + acclb[2]) * xvb.z : pb2; \
    float nb3 = (mi != 0.0f) ? (acchb[3] + acclb[3]) * xvb.w : pb3; \
    if (RN) { \
        unsigned short u = Pp[r * PSTR]; \
        int Ex = (int)((u >> 7) & 255u) - 127; \
        float sc = __uint_as_float((unsigned)(127 - Ex) << 23); \
        na0 *= sc; na1 *= sc; na2 *= sc; na3 *= sc; \
        nb0 *= sc; nb1 *= sc; nb2 *= sc; nb3 *= sc; \
        m_int += Ex; \
    } \
    pa0 = na0; pa1 = na1; pa2 = na2; pa3 = na3; \
    pb0 = nb0; pb1 = nb1; pb2 = nb2; pb3 = nb3; \
    unsigned ql, qh; \
    asm volatile("v_cvt_pk_bf16_f32 %0, %1, %2" : "=v"(ql) : "v"(na0), "v"(na1)); \
    asm volatile("v_cvt_pk_bf16_f32 %0, %1, %2" : "=v"(qh) : "v"(na2), "v"(na3)); \
    *(uint2*)&Pn[r * PSTR + j0a] = make_uint2(ql, qh); \
    asm volatile("v_cvt_pk_bf16_f32 %0, %1, %2" : "=v"(ql) : "v"(nb0), "v"(nb1)); \
    asm volatile("v_cvt_pk_bf16_f32 %0, %1, %2" : "=v"(qh) : "v"(nb2), "v"(nb3)); \
    *(uint2*)&Pn[r * PSTR + j0b] = make_uint2(ql, qh); \
    BARSYNC(); }

    for (int c = 0; c < NCHUNK; ++c) {
        // prefetch next emission chunk into registers (raw; exp applied at store)
        float4 pf0, pf1, pf2, pf3, pf4, pf5, pf6, pf7; int mpre = 0;
        if (c + 1 < NCHUNK) {
            const size_t tb = (size_t)(c + 1) * CHUNK * KK;
            pf0 = *(const float4*)(gA + tb + 0 * (size_t)KK);
            pf1 = *(const float4*)(gB + tb + 0 * (size_t)KK);
            pf2 = *(const float4*)(gA + tb + 1 * (size_t)KK);
            pf3 = *(const float4*)(gB + tb + 1 * (size_t)KK);
            pf4 = *(const float4*)(gA + tb + 2 * (size_t)KK);
            pf5 = *(const float4*)(gB + tb + 2 * (size_t)KK);
            pf6 = *(const float4*)(gA + tb + 3 * (size_t)KK);
            pf7 = *(const float4*)(gB + tb + 3 * (size_t)KK);
            if (tid < CHUNK * NB)
                mpre = mask[(size_t)(b0 + (tid & 15)) * TT + (c + 1) * CHUNK + (tid >> 4)];
        }
        const float* eb = ebuf[c & 1];
        const float* mb = mbuf[c & 1];
        if (c == 0) {
            STEP(1, 0) STEP(2, 0) STEP(3, 1)
        } else {
            STEP(0, 0) STEP(1, 0) STEP(2, 0) STEP(3, 1)
        }
        if (c + 1 < NCHUNK) {
            float* en = ebuf[(c + 1) & 1];
            XSTORE(en, pf0, 0) XSTORE(en, pf1, 1) XSTORE(en, pf2, 2) XSTORE(en, pf3, 3)
            XSTORE(en, pf4, 4) XSTORE(en, pf5, 5) XSTORE(en, pf6, 6) XSTORE(en, pf7, 7)
            if (tid < CHUNK * NB)
                mbuf[(c + 1) & 1][(tid >> 4) * NB + (tid & 15)] = (float)mpre;
            BARSYNC();
        }
    }
#undef STEP
#undef XSTORE

    // ---- denominator: per-batch LSE over j of (m*ln2 + log p) ----
    // Last chunk read ebuf[1]; ebuf[0] is free (16 x 128 fp32, plain layout).
    float* aw = ebuf[0];
    {
        const float c2 = 0.69314718055994531f;
        float4 av;
        av.x = (float)m_int * c2 + logf(pa0);
        av.y = (float)m_int * c2 + logf(pa1);
        av.z = (float)m_int * c2 + logf(pa2);
        av.w = (float)m_int * c2 + logf(pa3);
        *(float4*)&aw[r * KK + j0a] = av;
        av.x = (float)m_int * c2 + logf(pb0);
        av.y = (float)m_int * c2 + logf(pb1);
        av.z = (float)m_int * c2 + logf(pb2);
        av.w = (float)m_int * c2 + logf(pb3);
        *(float4*)&aw[r * KK + j0b] = av;
    }
    BARSYNC();
    {
        int bq = tid >> 4, l16 = tid & 15;   // 16 lanes per batch (lane-aligned groups)
        const float* ab = aw + bq * KK;
        float4 v1 = *(const float4*)&ab[l16 * 8];
        float4 v2 = *(const float4*)&ab[l16 * 8 + 4];
        float mx = fmaxf(fmaxf(fmaxf(v1.x, v1.y), fmaxf(v1.z, v1.w)),
                         fmaxf(fmaxf(v2.x, v2.y), fmaxf(v2.z, v2.w)));
#pragma unroll
        for (int o = 1; o < 16; o <<= 1) mx = fmaxf(mx, __shfl_xor(mx, o));
        float ev = __expf(v1.x - mx) + __expf(v1.y - mx) + __expf(v1.z - mx) + __expf(v1.w - mx)
                 + __expf(v2.x - mx) + __expf(v2.y - mx) + __expf(v2.z - mx) + __expf(v2.w - mx);
#pragma unroll
        for (int o = 1; o < 16; o <<= 1) ev += __shfl_xor(ev, o);
        if (l16 == 0) atomicAdd(out, -(mx + logf(ev)));
    }
}

// ---------------- numerator (gold-path) kernel: 256 blocks x 256 threads ----------------
__global__ __launch_bounds__(256, 1) void crf_num(
    const float* __restrict__ inputs,
    const float* __restrict__ trans,
    const int* __restrict__ tags,
    const int* __restrict__ mask,
    float* __restrict__ out)
{
    __shared__ float scratch[8];
    const int tid = threadIdx.x;
    const int b = blockIdx.x;
    const float* binp = inputs + (size_t)b * TT * KK;
    const int* bmask  = mask + (size_t)b * TT;
    const int* btags  = tags + (size_t)b * TT;
    float numpart = 0.0f, maskpart = 0.0f;
#pragma unroll
    for (int kk2 = 0; kk2 < TT / 256; ++kk2) {
        int t = tid + 256 * kk2;
        int tg = btags[t];
        float mf = (float)bmask[t];
        maskpart += mf;
        if (t < TT - 1) {
            int tg1   = btags[t + 1];
            float mf1 = (float)bmask[t + 1];
            numpart += trans[tg * KK + tg1] * mf1;
            numpart += binp[(size_t)t * KK + tg] * mf;
        }
    }
#pragma unroll
    for (int o = 1; o < 64; o <<= 1) numpart += __shfl_xor(numpart, o);
#pragma unroll
    for (int o = 1; o < 64; o <<= 1) maskpart += __shfl_xor(maskpart, o);
    if ((tid & 63) == 0) {
        scratch[tid >> 6]     = numpart;
        scratch[4 + (tid >> 6)] = maskpart;
    }
    __syncthreads();
    if (tid == 0) {
        float num  = (scratch[0] + scratch[1]) + (scratch[2] + scratch[3]);
        float msum = (scratch[4] + scratch[5]) + (scratch[6] + scratch[7]);
        int last_idx = (int)msum - 1;
        int ltag = btags[last_idx];
        num += binp[(size_t)(TT - 1) * KK + ltag] * (float)bmask[TT - 1];
        atomicAdd(out, num);
    }
}

extern "C" void kernel_launch(void* const* d_in, const int* in_sizes, int n_in,
                              void* d_out, int out_size, void* d_ws, size_t ws_size,
                              hipStream_t stream) {
    const float* inputs = (const float*)d_in[0];
    const float* trans  = (const float*)d_in[1];
    const int* tagsp    = (const int*)d_in[2];
    const int* maskp    = (const int*)d_in[3];
    float* out          = (float*)d_out;
    zero_out_kernel<<<1, 1, 0, stream>>>(out);
    crf_num<<<BB, 256, 0, stream>>>(inputs, trans, tagsp, maskp, out);
    crf_fwd<<<NBLK, NTHR, 0, stream>>>(inputs, trans, maskp, out);
}

// Round 7
// 756.598 us; speedup vs baseline: 1.2007x; 1.2007x over previous
//
#include <hip/hip_runtime.h>
#include <math.h>

#define BB 256
#define TT 1024
#define KK 128
#define NTHR 1024
#define CHUNK 32
#define NCHUNK (TT / CHUNK)   // 32

__global__ void zero_out_kernel(float* out) { out[0] = 0.0f; }

// LGKM-only barrier: LDS is the only cross-wave dependency in the hot loop;
// global prefetch loads stay in flight across step barriers (never drain vmcnt).
#define BARSYNC() { asm volatile("s_waitcnt lgkmcnt(0)" ::: "memory"); \
                    __builtin_amdgcn_s_barrier(); \
                    asm volatile("" ::: "memory"); }

// One block per batch, 1024 threads (16 waves = 4/SIMD for latency hiding).
// j = tid>>3 (output state), q = tid&7 (16-wide i-octant). P stored fp32 in LDS;
// all 8 lanes of a j-group read the SAME P slice -> LDS broadcast, zero conflicts,
// and no bf16 pack/unpack VALU (R1's dominant cost). E = exp(trans) fp32 in 4
// float4 regs/thread. X = exp(emit) staged in LDS, 32-step chunks, double-buffered.
// Renorm by exact pow2 of P_prev[0]'s exponent every 4th step; numerator fused.
__global__ __launch_bounds__(NTHR, 1) void crf_kernel(
    const float* __restrict__ inputs,      // B*T*K fp32
    const float* __restrict__ trans,       // K*K fp32
    const int* __restrict__ tags,          // B*T int32 view
    const int* __restrict__ mask,          // B*T int32
    float* __restrict__ out)               // scalar
{
    __shared__ __align__(16) float pbuf[2][KK];        // fp32 P, double-buffered
    __shared__ __align__(16) float ebuf[2][CHUNK*KK];  // X = exp(emissions)
    __shared__ float mbuf[2][CHUNK];
    __shared__ float scratch[32];

    const int tid = threadIdx.x;
    const int j   = tid >> 3;    // 0..127
    const int q   = tid & 7;     // 0..7
    const int b   = blockIdx.x;

    const float* binp = inputs + (size_t)b * TT * KK;
    const int* bmask  = mask + (size_t)b * TT;
    const int* btags  = tags + (size_t)b * TT;

    // ---- E: exp(trans[q*16+k][j]), k = 0..15, in 4 float4 regs ----
    float4 E0, E1, E2, E3;
    {
        const float* tc = trans + (size_t)(q * 16) * KK + j;
        E0.x = expf(tc[0*KK]);  E0.y = expf(tc[1*KK]);  E0.z = expf(tc[2*KK]);  E0.w = expf(tc[3*KK]);
        E1.x = expf(tc[4*KK]);  E1.y = expf(tc[5*KK]);  E1.z = expf(tc[6*KK]);  E1.w = expf(tc[7*KK]);
        E2.x = expf(tc[8*KK]);  E2.y = expf(tc[9*KK]);  E2.z = expf(tc[10*KK]); E2.w = expf(tc[11*KK]);
        E3.x = expf(tc[12*KK]); E3.y = expf(tc[13*KK]); E3.z = expf(tc[14*KK]); E3.w = expf(tc[15*KK]);
    }

    // ---- stage chunk 0 of X = exp(emissions), + mask ----
    {
        float4 e4 = ((const float4*)binp)[tid];   // 1024 * 4 floats = 32 steps * 128
        e4.x = __expf(e4.x); e4.y = __expf(e4.y);
        e4.z = __expf(e4.z); e4.w = __expf(e4.w);
        ((float4*)ebuf[0])[tid] = e4;
    }
    if (tid < CHUNK) mbuf[0][tid] = (float)bmask[tid];
    BARSYNC();

    // ---- t = 0: p = exp(alpha0) = X[0][j], m = 0 ----
    float pcur = ebuf[0][j];
    int m_int = 0;
    if (q == 0) pbuf[0][j] = pcur;
    BARSYNC();

    for (int c = 0; c < NCHUNK; ++c) {
        // prefetch next emission chunk into registers (raw; exp applied at store)
        float4 epre; int mpre = 0;
        if (c + 1 < NCHUNK) {
            epre = ((const float4*)(binp + (size_t)(c + 1) * CHUNK * KK))[tid];
            if (tid < CHUNK) mpre = bmask[(c + 1) * CHUNK + tid];
        }
        const float* eb = ebuf[c & 1];
        const float* mb = mbuf[c & 1];
        for (int s = (c == 0) ? 1 : 0; s < CHUNK; ++s) {
            const int t = c * CHUNK + s;
            const float* Pp = pbuf[(t - 1) & 1];
            const float4* pr = (const float4*)(Pp + q * 16);
            float4 p0 = pr[0], p1 = pr[1], p2 = pr[2], p3 = pr[3];
            // 4 independent 4-deep FMA chains + tree
            float z0 = p0.x * E0.x; z0 = fmaf(p0.y, E0.y, z0);
            z0 = fmaf(p0.z, E0.z, z0); z0 = fmaf(p0.w, E0.w, z0);
            float z1 = p1.x * E1.x; z1 = fmaf(p1.y, E1.y, z1);
            z1 = fmaf(p1.z, E1.z, z1); z1 = fmaf(p1.w, E1.w, z1);
            float z2 = p2.x * E2.x; z2 = fmaf(p2.y, E2.y, z2);
            z2 = fmaf(p2.z, E2.z, z2); z2 = fmaf(p2.w, E2.w, z2);
            float z3 = p3.x * E3.x; z3 = fmaf(p3.y, E3.y, z3);
            z3 = fmaf(p3.z, E3.z, z3); z3 = fmaf(p3.w, E3.w, z3);
            float z = (z0 + z1) + (z2 + z3);
            z += __shfl_xor(z, 1);     // combine the 8 i-octants
            z += __shfl_xor(z, 2);
            z += __shfl_xor(z, 4);
            float X  = eb[s * KK + j];   // broadcast among the 8 q-lanes
            float mi = mb[s];            // uniform across block
            float pn = (mi != 0.0f) ? z * X : pcur;   // mask-hold (mi in {0,1})
            if ((s & 3) == 3) {
                // renorm: exact pow2 from fp32 P_prev[0]'s exponent (uniform).
                // Any uniform scale keeps alpha = log(p) + m*ln2 invariant.
                unsigned u = __float_as_uint(Pp[0]);
                int Ex = (int)((u >> 23) & 255u) - 127;
                float sc = __uint_as_float((unsigned)(127 - Ex) << 23);   // 2^-Ex
                pn *= sc;
                m_int += Ex;
            }
            pcur = pn;
            if (q == 0) pbuf[t & 1][j] = pn;
            BARSYNC();
        }
        if (c + 1 < NCHUNK) {
            epre.x = __expf(epre.x); epre.y = __expf(epre.y);
            epre.z = __expf(epre.z); epre.w = __expf(epre.w);
            ((float4*)ebuf[(c + 1) & 1])[tid] = epre;
            if (tid < CHUNK) mbuf[(c + 1) & 1][tid] = (float)mpre;
            BARSYNC();
        }
    }

    // ---- denominator: LSE over j of (m*ln2 + log p) ----
    // Last chunk read ebuf[1]; ebuf[0] is free for alpha staging.
    float* aw = ebuf[0];
    if (q == 0) aw[j] = (float)m_int * 0.69314718055994531f + logf(pcur);
    BARSYNC();
    float den = 0.0f;
    if (tid < 64) {
        float a0 = aw[tid], a1 = aw[tid + 64];
        float mx = fmaxf(a0, a1);
#pragma unroll
        for (int o = 1; o < 64; o <<= 1) mx = fmaxf(mx, __shfl_xor(mx, o));
        float ev = __expf(a0 - mx) + __expf(a1 - mx);
#pragma unroll
        for (int o = 1; o < 64; o <<= 1) ev += __shfl_xor(ev, o);
        den = mx + logf(ev);   // valid in all 64 lanes; tid 0 uses it
    }

    // ---- numerator (gold-path score): one t per thread ----
    float numpart = 0.0f, maskpart = 0.0f;
    {
        int t = tid;                       // NTHR == TT
        int tg = btags[t];
        float mf = (float)bmask[t];
        maskpart = mf;
        if (t < TT - 1) {
            numpart = trans[tg * KK + btags[t + 1]] * (float)bmask[t + 1]
                    + binp[(size_t)t * KK + tg] * mf;
        }
    }
#pragma unroll
    for (int o = 1; o < 64; o <<= 1) numpart  += __shfl_xor(numpart, o);
#pragma unroll
    for (int o = 1; o < 64; o <<= 1) maskpart += __shfl_xor(maskpart, o);
    if ((tid & 63) == 0) {
        scratch[tid >> 6]      = numpart;
        scratch[16 + (tid >> 6)] = maskpart;
    }
    BARSYNC();
    if (tid == 0) {
        float num = 0.0f, msum = 0.0f;
#pragma unroll
        for (int k2 = 0; k2 < 16; ++k2) { num += scratch[k2]; msum += scratch[16 + k2]; }
        int last_idx = (int)msum - 1;
        int ltag = btags[last_idx];
        num += binp[(size_t)(TT - 1) * KK + ltag] * (float)bmask[TT - 1];
        atomicAdd(out, num - den);
    }
}

extern "C" void kernel_launch(void* const* d_in, const int* in_sizes, int n_in,
                              void* d_out, int out_size, void* d_ws, size_t ws_size,
                              hipStream_t stream) {
    const float* inputs = (const float*)d_in[0];
    const float* trans  = (const float*)d_in[1];
    const int* tagsp    = (const int*)d_in[2];
    const int* maskp    = (const int*)d_in[3];
    float* out          = (float*)d_out;
    zero_out_kernel<<<1, 1, 0, stream>>>(out);
    crf_kernel<<<BB, NTHR, 0, stream>>>(inputs, trans, tagsp, maskp, out);
}